// Round 5
// baseline (54.166 us; speedup 1.0000x reference)
//
#include <hip/hip_runtime.h>
#include <math.h>

#define N_BOX 8192
#define NT 1024
#define MAX_TOPK 128
#define IOU_THR 0.3f
#define M_TARGET 400u
#define CAP 1024
#define BIN_SHIFT 19      // top 13 bits -> 8192 bins

// ws layout: [0, 128K) float4 boxes[8192]; [128K, 160K) u32 keys[8192]
#define WS_BOXES_OFF 0
#define WS_KEYS_OFF  (N_BOX * 16)

__device__ __forceinline__ float bcast_f(float v, int srclane) {
    return __uint_as_float((unsigned)__builtin_amdgcn_readlane(__float_as_uint(v), srclane));
}
__device__ __forceinline__ int bcast_i(int v, int srclane) {
    return __builtin_amdgcn_readlane(v, srclane);
}

// ---------------- K1: parallel decode + 32-bit sort-key build ----------------
__global__ void decode_kernel(const float* __restrict__ x,
                              const float* __restrict__ y,
                              const float* __restrict__ anchors,
                              float4* __restrict__ boxes,
                              unsigned* __restrict__ keys)
{
#pragma clang fp contract(off)
    int i = blockIdx.x * blockDim.x + threadIdx.x;
    if (i >= N_BOX) return;

    float s = 1.0f / (1.0f + expf(-x[i]));
    // s in (0,1): sortable-ascending = bits|sign; invert for descending score
    unsigned k32 = ~(__float_as_uint(s) | 0x80000000u);
    keys[i] = k32;

    const float inv128 = 0.0078125f;
    const float2* yr = (const float2*)(y + i * 18);
    float2 ya = yr[0];
    float2 yb = yr[1];
    float2 an = ((const float2*)anchors)[i];
    float cx = ya.x * inv128 + an.x;
    float cy = ya.y * inv128 + an.y;
    float w2 = (yb.x * inv128) * 0.5f;
    float h2 = (yb.y * inv128) * 0.5f;
    boxes[i] = make_float4(cx - w2, cy - h2, cx + w2, cy + h2);
}

// ---------------- K2: select top-M, rank-sort, NMS, output ----------------
__global__ __launch_bounds__(NT)
void topk_nms_kernel(const float* __restrict__ x,
                     const float* __restrict__ y,
                     const float* __restrict__ anchors,
                     const unsigned* __restrict__ keys,
                     const float4* __restrict__ boxes,
                     float* __restrict__ out,
                     int top_k)
{
#pragma clang fp contract(off)
    __shared__ unsigned s_hist[N_BOX];              // 32 KB (8192 bins)
    __shared__ unsigned s_waveexcl[17];
    __shared__ unsigned long long s_cand[CAP];      // 8 KB
    __shared__ unsigned long long s_sorted[CAP];    // 8 KB
    __shared__ float4 s_box[CAP];                   // 16 KB
    __shared__ int s_keep[MAX_TOPK];
    __shared__ int s_cnt, s_B, s_C, s_nkept;

    const int tid = threadIdx.x;
    const int lane = tid & 63;
    const int wv = tid >> 6;

    // ---- load my 8 keys into registers (coalesced uint4 x2) ----
    const uint4* kp = (const uint4*)keys;
    uint4 ka = kp[tid * 2 + 0];
    uint4 kb = kp[tid * 2 + 1];
    unsigned myk[8] = {ka.x, ka.y, ka.z, ka.w, kb.x, kb.y, kb.z, kb.w};

    if (tid == 0) { s_cnt = 0; s_nkept = 0; }
    {   // zero histogram with b128 stores; init cand pad
        uint4 z = make_uint4(0u, 0u, 0u, 0u);
        uint4* hp = (uint4*)s_hist;
        hp[tid * 2 + 0] = z;
        hp[tid * 2 + 1] = z;
        s_cand[tid] = ~0ull;        // pad value, > any real key
    }
    __syncthreads();

    // ---- histogram on top 13 bits ----
#pragma unroll
    for (int k = 0; k < 8; k++)
        atomicAdd(&s_hist[myk[k] >> BIN_SHIFT], 1u);
    __syncthreads();

    // ---- scan: find bin B containing the M_TARGET-th smallest ----
    uint4 h0 = ((const uint4*)s_hist)[tid * 2 + 0];
    uint4 h1 = ((const uint4*)s_hist)[tid * 2 + 1];
    unsigned binv[8] = {h0.x, h0.y, h0.z, h0.w, h1.x, h1.y, h1.z, h1.w};
    unsigned csum = binv[0] + binv[1] + binv[2] + binv[3]
                  + binv[4] + binv[5] + binv[6] + binv[7];

    unsigned incl = csum;
    for (int off = 1; off < 64; off <<= 1) {
        unsigned n = __shfl_up(incl, off);
        if (lane >= off) incl += n;
    }
    if (lane == 63) s_waveexcl[wv + 1] = incl;
    __syncthreads();
    if (wv == 0) {                       // 16-lane shuffle scan of wave totals
        unsigned t = (lane < 16) ? s_waveexcl[lane + 1] : 0u;
        unsigned v = t;
        for (int off = 1; off < 16; off <<= 1) {
            unsigned n = __shfl_up(v, off);
            if (lane >= off) v += n;
        }
        if (lane < 16) s_waveexcl[lane] = v - t;   // exclusive
    }
    __syncthreads();

    unsigned myexcl = s_waveexcl[wv] + incl - csum;
    if (myexcl < M_TARGET && myexcl + csum >= M_TARGET) {
        unsigned run = myexcl;
#pragma unroll
        for (int k = 0; k < 8; k++) {
            run += binv[k];
            if (run >= M_TARGET) { s_B = tid * 8 + k; s_C = (int)run; break; }
        }
    }
    __syncthreads();

    const int B = s_B;
    int C = s_C; if (C > CAP) C = CAP;

    // ---- compact candidates (bin <= B) from registers ----
#pragma unroll
    for (int k = 0; k < 8; k++) {
        if ((int)(myk[k] >> BIN_SHIFT) <= B) {
            int p = atomicAdd(&s_cnt, 1);
            if (p < CAP)
                s_cand[p] = (((unsigned long long)myk[k]) << 32) | (unsigned)(tid * 8 + k);
        }
    }
    __syncthreads();

    // ---- rank sort, unrolled x8 via b128 broadcast reads ----
    const int Cpad = (C + 7) & ~7;
    if (tid < C) {
        unsigned long long me = s_cand[tid];
        int rank = 0;
        const ulonglong2* cp = (const ulonglong2*)s_cand;
        for (int j = 0; j < Cpad; j += 8) {
            ulonglong2 a = cp[(j >> 1) + 0];
            ulonglong2 b = cp[(j >> 1) + 1];
            ulonglong2 d = cp[(j >> 1) + 2];
            ulonglong2 e = cp[(j >> 1) + 3];
            rank += (a.x < me) + (a.y < me) + (b.x < me) + (b.y < me)
                  + (d.x < me) + (d.y < me) + (e.x < me) + (e.y < me);
        }
        s_sorted[rank] = me;
    }
    __syncthreads();

    // ---- gather candidate boxes (parallel) ----
    if (tid < C) {
        int idx = (int)(unsigned)(s_sorted[tid] & 0xFFFFFFFFull);
        s_box[tid] = boxes[idx];
    }
    __syncthreads();

    // ---- wave-0 NMS: all state in named registers (no runtime-indexed arrays) ----
    if (wv == 0) {
        float k0x1 = 0.f, k0y1 = 0.f, k0x2 = 0.f, k0y2 = 0.f, k0a = 0.f;  // slot = lane
        float k1x1 = 0.f, k1y1 = 0.f, k1x2 = 0.f, k1y2 = 0.f, k1a = 0.f;  // slot = lane+64
        int nkept = 0;
        int base = 0;
        float4 bb = s_box[lane];
        int bidx = (int)(unsigned)(s_sorted[lane] & 0xFFFFFFFFull);

        int c = 0;
        while (c < C && nkept < top_k) {
            int p = c - base;
            if (p == 64) {
                base += 64; p = 0;
                int g = base + lane;          // < CAP by construction
                bb = s_box[g];
                bidx = (int)(unsigned)(s_sorted[g] & 0xFFFFFFFFull);
            }
            // p is wave-uniform -> cheap v_readlane broadcast
            float cx1 = bcast_f(bb.x, p);
            float cy1 = bcast_f(bb.y, p);
            float cx2 = bcast_f(bb.z, p);
            float cy2 = bcast_f(bb.w, p);
            int  cidx = bcast_i(bidx, p);
            float carea = (cx2 - cx1) * (cy2 - cy1);

            bool hit = false;
            if (lane < nkept) {
                float iw = fmaxf(fminf(k0x2, cx2) - fmaxf(k0x1, cx1), 0.0f);
                float ih = fmaxf(fminf(k0y2, cy2) - fmaxf(k0y1, cy1), 0.0f);
                float inter = iw * ih;
                float iou = inter / (k0a + carea - inter);
                if (iou > IOU_THR) hit = true;
            }
            if (lane + 64 < nkept) {
                float iw = fmaxf(fminf(k1x2, cx2) - fmaxf(k1x1, cx1), 0.0f);
                float ih = fmaxf(fminf(k1y2, cy2) - fmaxf(k1y1, cy1), 0.0f);
                float inter = iw * ih;
                float iou = inter / (k1a + carea - inter);
                if (iou > IOU_THR) hit = true;
            }
            unsigned long long m = __ballot(hit);
            if (m == 0ull) {
                if (nkept < 64) {
                    if (lane == nkept) {
                        k0x1 = cx1; k0y1 = cy1; k0x2 = cx2; k0y2 = cy2; k0a = carea;
                    }
                } else {
                    if (lane == nkept - 64) {
                        k1x1 = cx1; k1y1 = cy1; k1x2 = cx2; k1y2 = cy2; k1a = carea;
                    }
                }
                if (lane == 0) s_keep[nkept] = cidx;
                nkept++;
            }
            c++;
        }
        if (lane == 0) s_nkept = nkept;
    }
    __syncthreads();

    // ---- output: [score, det0, det1, det2, det4, det5, det8, det9] ----
    const float inv128 = 0.0078125f;
    const int nkept = s_nkept;
    const int total = top_k * 8;
    for (int t = tid; t < total; t += NT) {
        int r = t >> 3;
        int col = t & 7;
        float v = 0.0f;
        if (r < nkept) {
            int idx = s_keep[r];
            if (col == 0) {
                v = 1.0f / (1.0f + expf(-x[idx]));
            } else {
                // col 1..7 -> j in {0,1,2,4,5,8,9} (no runtime-indexed local array)
                int j = (col <= 3) ? (col - 1) : ((col <= 5) ? col : (col + 2));
                float a;
                if (j == 2) a = 0.0f;
                else        a = (j & 1) ? anchors[idx * 2 + 1] : anchors[idx * 2 + 0];
                v = y[idx * 18 + j] * inv128 + a;
            }
        }
        out[t] = v;
    }
}

extern "C" void kernel_launch(void* const* d_in, const int* in_sizes, int n_in,
                              void* d_out, int out_size, void* d_ws, size_t ws_size,
                              hipStream_t stream) {
    const float* x       = (const float*)d_in[0];   // (1, 8192, 1)
    const float* y       = (const float*)d_in[1];   // (1, 8192, 18)
    const float* anchors = (const float*)d_in[2];   // (8192, 2)
    float* out = (float*)d_out;                     // (top_k, 8) f32

    float4* boxes = (float4*)((char*)d_ws + WS_BOXES_OFF);       // 128 KB
    unsigned* keys = (unsigned*)((char*)d_ws + WS_KEYS_OFF);     // 32 KB

    int top_k = out_size / 8;
    if (top_k > MAX_TOPK) top_k = MAX_TOPK;

    decode_kernel<<<N_BOX / 256, 256, 0, stream>>>(x, y, anchors, boxes, keys);
    topk_nms_kernel<<<1, NT, 0, stream>>>(x, y, anchors, keys, boxes, out, top_k);
}